// Round 3
// baseline (475.455 us; speedup 1.0000x reference)
//
#include <hip/hip_runtime.h>
#include <hip/hip_bf16.h>
#include <cstdint>
#include <cstddef>

// B=4, S=2048, D=1024. Input dtype detected at runtime (fp32 vs bf16) because
// the harness dtype is ambiguous; all internal compute is bf16 MFMA.
//
// Pipeline:
//   0. detect_mode: flag=1 if inputs are fp32 (mantissa-half heuristic on X)
//   1. convert_small: bq,bk,bv,gamma,beta -> bf16 staging
//   2. convert_x:     X -> Xb bf16 [8192][1024]
//   3. transpose_w:   Wt[3072][1024] = W_{q,k,v}^T (bf16, mode-aware load)
//   4. gemm_bt<0>:    QKV[8192][3072] = Xb @ Wt^T + bias          (bf16)
//   per batch b:
//   5. gemm_bt<1>:    S[2048][2048] = (Q_b @ K_b^T)/32 -> fp32 in d_out
//   6. softmax:       P = softmax_row(S) bf16, in-place overlay (stride 4096)
//   7. transpose_vb:  Vt_b[1024][2048] = V_b^T
//   8. gemm_bt<2>:    Ctx_b = P @ V_b -> overwrites dead Q slots of QKV
//   9. resid_ln:      out = LN(Ctx + Xb)*gamma + beta  (bf16 or fp32 store)
//
// d_ws layout (16B-aligned, total ~77.6 MB):
//   flag  @ 0            16 B
//   bias5 @ 16           5*2048 B (bq,bk,bv,gamma,beta as bf16)
//   Wt    @ 16,384       6,291,456
//   QKV   @ 6,307,840    50,331,648
//   Vtb   @ 56,639,488   4,194,304
//   Xb    @ 60,833,792   16,777,216

typedef unsigned short u16;
using bf16x8 = __attribute__((ext_vector_type(8))) short;
using f32x4  = __attribute__((ext_vector_type(4))) float;

__device__ __forceinline__ float bf2f(u16 h) {
    union { unsigned int u; float f; } c;
    c.u = ((unsigned int)h) << 16;
    return c.f;
}
__device__ __forceinline__ u16 f2bf(float f) {
    union { float f; unsigned int u; } c;
    c.f = f;
    return (u16)((c.u + 0x7fffu + ((c.u >> 16) & 1u)) >> 16);  // RNE
}

// ------------------------------------------------------------- mode detection
// Even-index u16s of X: bf16 input -> real ~N(0,1) samples (small, not all 0).
// fp32 input -> low mantissa halves (pseudo-random; some decode huge/NaN).
__global__ void detect_mode_kernel(const u16* __restrict__ X, int* __restrict__ flag)
{
    const int lane = threadIdx.x;      // 64 threads
    bool bad = false, nz = false;
    for (int j = 0; j < 4; ++j) {
        float v = bf2f(X[(lane * 4 + j) * 2]);
        if (!(fabsf(v) <= 1e9f)) bad = true;   // catches NaN/inf/huge
        if (v != 0.f) nz = true;
    }
    unsigned long long anybad = __ballot(bad);
    unsigned long long anynz  = __ballot(nz);
    if (lane == 0) *flag = (anybad != 0ull || anynz == 0ull) ? 1 : 0;
}

// --------------------------------------------------- small vectors -> bf16
// grid 5 (bq,bk,bv,gamma,beta), block 256, 4 elems/thread.
__global__ __launch_bounds__(256) void convert_small_kernel(
    const void* s0, const void* s1, const void* s2, const void* s3,
    const void* s4, u16* __restrict__ dst, const int* __restrict__ flag)
{
    const void* srcs[5] = {s0, s1, s2, s3, s4};
    const void* src = srcs[blockIdx.x];
    u16* d = dst + (size_t)blockIdx.x * 1024;
    const int i = threadIdx.x * 4;
    if (*flag) {
        const float* f = (const float*)src;
        ushort4 o;
        o.x = f2bf(f[i]); o.y = f2bf(f[i + 1]);
        o.z = f2bf(f[i + 2]); o.w = f2bf(f[i + 3]);
        *(ushort4*)(d + i) = o;
    } else {
        *(ushort4*)(d + i) = *(const ushort4*)((const u16*)src + i);
    }
}

// --------------------------------------------------------------- X -> bf16
// grid 4096, block 256, 8 elems/thread (8M total).
__global__ __launch_bounds__(256) void convert_x_kernel(
    const void* __restrict__ X, u16* __restrict__ Xb, const int* __restrict__ flag)
{
    const size_t i = ((size_t)blockIdx.x * 256 + threadIdx.x) * 8;
    if (*flag) {
        const float* f = (const float*)X;
        float4 a = *(const float4*)(f + i);
        float4 b = *(const float4*)(f + i + 4);
        ushort4 o0, o1;
        o0.x = f2bf(a.x); o0.y = f2bf(a.y); o0.z = f2bf(a.z); o0.w = f2bf(a.w);
        o1.x = f2bf(b.x); o1.y = f2bf(b.y); o1.z = f2bf(b.z); o1.w = f2bf(b.w);
        *(ushort4*)(Xb + i) = o0;
        *(ushort4*)(Xb + i + 4) = o1;
    } else {
        *(uint4*)(Xb + i) = *(const uint4*)((const u16*)X + i);
    }
}

// ---------------------------------------------------------------- transpose W
// 64x64 tile transpose via LDS, mode-aware source load. grid (16,16,3).
__global__ __launch_bounds__(256) void transpose_w_kernel(
    const void* __restrict__ Wq, const void* __restrict__ Wk,
    const void* __restrict__ Wv, u16* __restrict__ Wt,
    const int* __restrict__ flag)
{
    __shared__ u16 tile[64][72];
    const int t  = threadIdx.x;
    const int k0 = blockIdx.x * 64;
    const int n0 = blockIdx.y * 64;
    const int w  = blockIdx.z;
    const void* W = (w == 0) ? Wq : ((w == 1) ? Wk : Wv);
    const int fp32 = *flag;
#pragma unroll
    for (int it = 0; it < 2; ++it) {
        int idx = t + it * 256;
        int r = idx >> 3;               // k-local
        int c = (idx & 7) * 8;          // n-local group
        const size_t off = (size_t)(k0 + r) * 1024 + n0 + c;
        if (fp32) {
            const float* Wf = (const float*)W + off;
            float4 a = *(const float4*)Wf;
            float4 b = *(const float4*)(Wf + 4);
            u16* tp = &tile[r][c];
            tp[0] = f2bf(a.x); tp[1] = f2bf(a.y); tp[2] = f2bf(a.z); tp[3] = f2bf(a.w);
            tp[4] = f2bf(b.x); tp[5] = f2bf(b.y); tp[6] = f2bf(b.z); tp[7] = f2bf(b.w);
        } else {
            *(uint4*)&tile[r][c] = *(const uint4*)((const u16*)W + off);
        }
    }
    __syncthreads();
#pragma unroll
    for (int it = 0; it < 2; ++it) {
        int idx = t + it * 256;
        int r = idx >> 3;               // n-local (output row)
        int c = (idx & 7) * 8;          // k-local group
        union { u16 s[8]; uint4 v; } tmp;
#pragma unroll
        for (int j = 0; j < 8; ++j) tmp.s[j] = tile[c + j][r];
        *(uint4*)(Wt + (size_t)(w * 1024 + n0 + r) * 1024 + k0 + c) = tmp.v;
    }
}

// ------------------------------------------------------------- transpose V_b
__global__ __launch_bounds__(256) void transpose_vb_kernel(
    const u16* __restrict__ QKV, u16* __restrict__ Vt, int b)
{
    __shared__ u16 tile[64][72];
    const int t  = threadIdx.x;
    const int k0 = blockIdx.x * 64;     // s
    const int n0 = blockIdx.y * 64;     // d
    const u16* Vsrc = QKV + (size_t)b * 2048 * 3072 + 2048;
#pragma unroll
    for (int it = 0; it < 2; ++it) {
        int idx = t + it * 256;
        int r = idx >> 3;
        int c = (idx & 7) * 8;
        *(uint4*)&tile[r][c] = *(const uint4*)(Vsrc + (size_t)(k0 + r) * 3072 + n0 + c);
    }
    __syncthreads();
#pragma unroll
    for (int it = 0; it < 2; ++it) {
        int idx = t + it * 256;
        int r = idx >> 3;
        int c = (idx & 7) * 8;
        union { u16 s[8]; uint4 v; } tmp;
#pragma unroll
        for (int j = 0; j < 8; ++j) tmp.s[j] = tile[c + j][r];
        *(uint4*)(Vt + (size_t)(n0 + r) * 2048 + k0 + c) = tmp.v;
    }
}

// ---------------------------------------------------------------- GEMM (B^T)
// C[M][N] = A[M][K] @ Bt[N][K]^T, bf16 in, fp32 accum.
// EPI 0: bf16 out + bias (bf16 bias table, 3x1024)  EPI 1: fp32 out, scaled
// EPI 2: bf16 out. Tile 64x64, BK=32, 4 waves of 2x2 16x16x32 MFMAs.
template<int EPI>
__global__ __launch_bounds__(256) void gemm_bt(
    const u16* __restrict__ A, int lda,
    const u16* __restrict__ Bt, int ldb,
    void* __restrict__ Cp, int ldc, int K, float scale,
    const u16* __restrict__ bias3)
{
    __shared__ u16 As[64][40];
    __shared__ u16 Bs[64][40];
    const int t    = threadIdx.x;
    const int lane = t & 63;
    const int w    = t >> 6;
    const int wr   = w >> 1, wc = w & 1;
    const int quad = lane >> 4, l16 = lane & 15;
    const int m0 = blockIdx.y * 64;
    const int n0 = blockIdx.x * 64;

    const int srow = t >> 2;
    const int scol = (t & 3) * 8;
    const u16* Ap = A  + (size_t)(m0 + srow) * lda + scol;
    const u16* Bp = Bt + (size_t)(n0 + srow) * ldb + scol;

    f32x4 acc00 = {0.f, 0.f, 0.f, 0.f};
    f32x4 acc01 = acc00, acc10 = acc00, acc11 = acc00;

    for (int k0 = 0; k0 < K; k0 += 32) {
        uint4 av = *(const uint4*)(Ap + k0);
        uint4 bv = *(const uint4*)(Bp + k0);
        *(uint4*)&As[srow][scol] = av;
        *(uint4*)&Bs[srow][scol] = bv;
        __syncthreads();
        bf16x8 a0 = *(const bf16x8*)&As[wr * 32 + l16][quad * 8];
        bf16x8 a1 = *(const bf16x8*)&As[wr * 32 + 16 + l16][quad * 8];
        bf16x8 q0 = *(const bf16x8*)&Bs[wc * 32 + l16][quad * 8];
        bf16x8 q1 = *(const bf16x8*)&Bs[wc * 32 + 16 + l16][quad * 8];
        acc00 = __builtin_amdgcn_mfma_f32_16x16x32_bf16(a0, q0, acc00, 0, 0, 0);
        acc01 = __builtin_amdgcn_mfma_f32_16x16x32_bf16(a0, q1, acc01, 0, 0, 0);
        acc10 = __builtin_amdgcn_mfma_f32_16x16x32_bf16(a1, q0, acc10, 0, 0, 0);
        acc11 = __builtin_amdgcn_mfma_f32_16x16x32_bf16(a1, q1, acc11, 0, 0, 0);
        __syncthreads();
    }

    // C/D layout: col = lane&15, row = quad*4 + reg  (m89-verified)
    const int row0 = m0 + wr * 32 + quad * 4;
    const int col0 = n0 + wc * 32 + l16;
    f32x4 accs[2][2] = {{acc00, acc01}, {acc10, acc11}};
#pragma unroll
    for (int mi = 0; mi < 2; ++mi) {
#pragma unroll
        for (int ni = 0; ni < 2; ++ni) {
            const int col = col0 + ni * 16;
            float bias = 0.f;
            if (EPI == 0) bias = bf2f(bias3[col]);   // bias3 = [bq|bk|bv] 3*1024
#pragma unroll
            for (int r = 0; r < 4; ++r) {
                const int row = row0 + mi * 16 + r;
                const float v = accs[mi][ni][r] * scale + bias;
                if (EPI == 1) ((float*)Cp)[(size_t)row * ldc + col] = v;
                else          ((u16*)Cp)[(size_t)row * ldc + col] = f2bf(v);
            }
        }
    }
}

// ---------------------------------------------------------------- softmax row
// fp32 S row -> bf16 P overlaid in first half of same row (stride 4096 u16).
__global__ __launch_bounds__(256) void softmax_kernel(float* __restrict__ S)
{
    const int row = blockIdx.x;
    const int t   = threadIdx.x;
    const float* sp = S + (size_t)row * 2048;
    float4 v0 = *(const float4*)(sp + t * 4);
    float4 v1 = *(const float4*)(sp + 1024 + t * 4);
    float vals[8] = {v0.x, v0.y, v0.z, v0.w, v1.x, v1.y, v1.z, v1.w};
    float m = vals[0];
#pragma unroll
    for (int i = 1; i < 8; ++i) m = fmaxf(m, vals[i]);
#pragma unroll
    for (int off = 32; off > 0; off >>= 1) m = fmaxf(m, __shfl_xor(m, off));
    __shared__ float red[8];
    const int w = t >> 6, lane = t & 63;
    if (lane == 0) red[w] = m;
    __syncthreads();
    m = fmaxf(fmaxf(red[0], red[1]), fmaxf(red[2], red[3]));
    float e[8];
    float s = 0.f;
#pragma unroll
    for (int i = 0; i < 8; ++i) { e[i] = __expf(vals[i] - m); s += e[i]; }
#pragma unroll
    for (int off = 32; off > 0; off >>= 1) s += __shfl_xor(s, off);
    if (lane == 0) red[4 + w] = s;
    __syncthreads();
    s = red[4] + red[5] + red[6] + red[7];
    const float rinv = 1.f / s;
    ushort4 o0, o1;
    o0.x = f2bf(e[0] * rinv); o0.y = f2bf(e[1] * rinv);
    o0.z = f2bf(e[2] * rinv); o0.w = f2bf(e[3] * rinv);
    o1.x = f2bf(e[4] * rinv); o1.y = f2bf(e[5] * rinv);
    o1.z = f2bf(e[6] * rinv); o1.w = f2bf(e[7] * rinv);
    u16* pp = (u16*)S + (size_t)row * 4096;
    __syncthreads();
    *(ushort4*)(pp + t * 4) = o0;
    *(ushort4*)(pp + 1024 + t * 4) = o1;
}

// ---------------------------------------------------------------- resid + LN
// Ctx in QKV Q-slots (stride 3072); X from Xb (bf16). Output dtype per flag.
__global__ __launch_bounds__(256) void resid_ln_kernel(
    const u16* __restrict__ Ctx, const u16* __restrict__ Xb,
    const u16* __restrict__ gamma, const u16* __restrict__ beta,
    void* __restrict__ Out, const int* __restrict__ flag)
{
    const size_t row = blockIdx.x;
    const int t = threadIdx.x;
    ushort4 cv = *(const ushort4*)(Ctx + row * 3072 + t * 4);
    ushort4 xv = *(const ushort4*)(Xb + row * 1024 + t * 4);
    float v[4] = {bf2f(cv.x) + bf2f(xv.x), bf2f(cv.y) + bf2f(xv.y),
                  bf2f(cv.z) + bf2f(xv.z), bf2f(cv.w) + bf2f(xv.w)};
    float s  = v[0] + v[1] + v[2] + v[3];
    float s2 = v[0] * v[0] + v[1] * v[1] + v[2] * v[2] + v[3] * v[3];
#pragma unroll
    for (int off = 32; off > 0; off >>= 1) {
        s  += __shfl_xor(s, off);
        s2 += __shfl_xor(s2, off);
    }
    __shared__ float red[8];
    const int w = t >> 6, lane = t & 63;
    if (lane == 0) { red[w] = s; red[4 + w] = s2; }
    __syncthreads();
    s  = red[0] + red[1] + red[2] + red[3];
    s2 = red[4] + red[5] + red[6] + red[7];
    const float mu  = s * (1.f / 1024.f);
    const float var = s2 * (1.f / 1024.f) - mu * mu;
    const float inv = rsqrtf(var + 1e-3f);
    ushort4 gv = *(const ushort4*)(gamma + t * 4);
    ushort4 bv = *(const ushort4*)(beta + t * 4);
    float o[4];
    o[0] = (v[0] - mu) * inv * bf2f(gv.x) + bf2f(bv.x);
    o[1] = (v[1] - mu) * inv * bf2f(gv.y) + bf2f(bv.y);
    o[2] = (v[2] - mu) * inv * bf2f(gv.z) + bf2f(bv.z);
    o[3] = (v[3] - mu) * inv * bf2f(gv.w) + bf2f(bv.w);
    if (*flag) {
        float4 fo = {o[0], o[1], o[2], o[3]};
        *(float4*)((float*)Out + row * 1024 + t * 4) = fo;
    } else {
        ushort4 bo;
        bo.x = f2bf(o[0]); bo.y = f2bf(o[1]); bo.z = f2bf(o[2]); bo.w = f2bf(o[3]);
        *(ushort4*)((u16*)Out + row * 1024 + t * 4) = bo;
    }
}

// ---------------------------------------------------------------- launch
extern "C" void kernel_launch(void* const* d_in, const int* in_sizes, int n_in,
                              void* d_out, int out_size, void* d_ws, size_t ws_size,
                              hipStream_t stream)
{
    (void)in_sizes; (void)n_in; (void)out_size; (void)ws_size;
    const void* X     = d_in[0];
    const void* Wq    = d_in[1];
    const void* bq    = d_in[2];
    const void* Wk    = d_in[3];
    const void* bk    = d_in[4];
    const void* Wv    = d_in[5];
    const void* bv    = d_in[6];
    const void* gamma = d_in[7];
    const void* beta  = d_in[8];

    char* ws = (char*)d_ws;
    int* flag   = (int*)(ws + 0);
    u16* bias5  = (u16*)(ws + 16);          // bq|bk|bv|gamma|beta, 1024 each
    u16* Wt     = (u16*)(ws + 16384);
    u16* QKV    = (u16*)(ws + 6307840);
    u16* Vtb    = (u16*)(ws + 56639488);
    u16* Xb     = (u16*)(ws + 60833792);
    float* S    = (float*)d_out;            // 16 MB scratch inside d_out
    u16* P      = (u16*)d_out;              // overlay, row stride 4096 u16

    detect_mode_kernel<<<1, 64, 0, stream>>>((const u16*)X, flag);
    convert_small_kernel<<<5, 256, 0, stream>>>(bq, bk, bv, gamma, beta, bias5, flag);
    convert_x_kernel<<<4096, 256, 0, stream>>>(X, Xb, flag);
    transpose_w_kernel<<<dim3(16, 16, 3), 256, 0, stream>>>(Wq, Wk, Wv, Wt, flag);

    gemm_bt<0><<<dim3(3072 / 64, 8192 / 64), 256, 0, stream>>>(
        Xb, 1024, Wt, 1024, QKV, 3072, 1024, 1.f, bias5);

    for (int b = 0; b < 4; ++b) {
        const u16* Qb = QKV + (size_t)b * 2048 * 3072;
        const u16* Kb = QKV + (size_t)b * 2048 * 3072 + 1024;
        u16* Ctxb = QKV + (size_t)b * 2048 * 3072;   // overwrite dead Q slots
        gemm_bt<1><<<dim3(2048 / 64, 2048 / 64), 256, 0, stream>>>(
            Qb, 3072, Kb, 3072, S, 2048, 1024, 0.03125f, nullptr);
        softmax_kernel<<<2048, 256, 0, stream>>>(S);
        transpose_vb_kernel<<<dim3(32, 16), 256, 0, stream>>>(QKV, Vtb, b);
        gemm_bt<2><<<dim3(1024 / 64, 2048 / 64), 256, 0, stream>>>(
            P, 4096, Vtb, 2048, Ctxb, 3072, 2048, 1.f, nullptr);
    }

    resid_ln_kernel<<<8192, 256, 0, stream>>>(
        QKV, Xb, bias5 + 3 * 1024, bias5 + 4 * 1024, d_out, flag);
}

// Round 4
// 332.451 us; speedup vs baseline: 1.4302x; 1.4302x over previous
//
#include <hip/hip_runtime.h>
#include <hip/hip_bf16.h>
#include <cstdint>
#include <cstddef>

// B=4, S=2048, D=1024. Inputs fp32 (runtime-detected, bf16 fallback kept).
// All GEMMs: m97-style 128x128 tile, BK=32, global_load_lds width-16 staging,
// 4 waves x (4x4) 16x16x32 bf16 MFMAs.
//
// Pipeline:
//   0. detect_mode; convert bias/gamma/beta + X -> bf16; transpose W -> Wt
//   1. gemm128<0>: QKV[8192][3072] = Xb @ Wt^T + bias               (bf16)
//   2. gemm128<1> z=4: S4[b][2048][2048] = (Q_b @ K_b^T)/32         (bf16)
//   3. softmax_bf16: in-place row softmax on S4 -> P                (bf16)
//   4. transpose_v4 z=4: Vt4[b][1024][2048] = V_b^T
//   5. gemm128<1> z=4: Ctx_b = P_b @ V_b -> dead Q slots of QKV     (bf16)
//   6. resid_ln: out = LN(Ctx + Xb)*gamma + beta (fp32 or bf16 store)
//
// d_ws layout (16B-aligned, ~118 MB):
//   flag  @ 0            16
//   bias5 @ 16           10,240   (bq|bk|bv|gamma|beta bf16)
//   Wt    @ 16,384       6,291,456
//   QKV   @ 6,307,840    50,331,648
//   Xb    @ 56,639,488   16,777,216
//   S4/P4 @ 73,416,704   33,554,432
//   Vt4   @ 106,971,136  16,777,216   (end 123,748,352)

typedef unsigned short u16;
using bf16x8 = __attribute__((ext_vector_type(8))) short;
using f32x4  = __attribute__((ext_vector_type(4))) float;

typedef __attribute__((address_space(3))) unsigned int lds_uint;
typedef const __attribute__((address_space(1))) unsigned int glob_uint;

__device__ __forceinline__ float bf2f(u16 h) {
    union { unsigned int u; float f; } c;
    c.u = ((unsigned int)h) << 16;
    return c.f;
}
__device__ __forceinline__ u16 f2bf(float f) {
    union { float f; unsigned int u; } c;
    c.f = f;
    return (u16)((c.u + 0x7fffu + ((c.u >> 16) & 1u)) >> 16);  // RNE
}
__device__ __forceinline__ void load_lds16(const void* g, void* l) {
    __builtin_amdgcn_global_load_lds((glob_uint*)g, (lds_uint*)l, 16, 0, 0);
}

// ------------------------------------------------------------- mode detection
__global__ void detect_mode_kernel(const u16* __restrict__ X, int* __restrict__ flag)
{
    const int lane = threadIdx.x;      // 64 threads
    bool bad = false, nz = false;
    for (int j = 0; j < 4; ++j) {
        float v = bf2f(X[(lane * 4 + j) * 2]);
        if (!(fabsf(v) <= 1e9f)) bad = true;
        if (v != 0.f) nz = true;
    }
    unsigned long long anybad = __ballot(bad);
    unsigned long long anynz  = __ballot(nz);
    if (lane == 0) *flag = (anybad != 0ull || anynz == 0ull) ? 1 : 0;
}

// --------------------------------------------------- small vectors -> bf16
__global__ __launch_bounds__(256) void convert_small_kernel(
    const void* s0, const void* s1, const void* s2, const void* s3,
    const void* s4, u16* __restrict__ dst, const int* __restrict__ flag)
{
    const void* srcs[5] = {s0, s1, s2, s3, s4};
    const void* src = srcs[blockIdx.x];
    u16* d = dst + (size_t)blockIdx.x * 1024;
    const int i = threadIdx.x * 4;
    if (*flag) {
        const float* f = (const float*)src;
        ushort4 o;
        o.x = f2bf(f[i]); o.y = f2bf(f[i + 1]);
        o.z = f2bf(f[i + 2]); o.w = f2bf(f[i + 3]);
        *(ushort4*)(d + i) = o;
    } else {
        *(ushort4*)(d + i) = *(const ushort4*)((const u16*)src + i);
    }
}

// --------------------------------------------------------------- X -> bf16
__global__ __launch_bounds__(256) void convert_x_kernel(
    const void* __restrict__ X, u16* __restrict__ Xb, const int* __restrict__ flag)
{
    const size_t i = ((size_t)blockIdx.x * 256 + threadIdx.x) * 8;
    if (*flag) {
        const float* f = (const float*)X;
        float4 a = *(const float4*)(f + i);
        float4 b = *(const float4*)(f + i + 4);
        ushort4 o0, o1;
        o0.x = f2bf(a.x); o0.y = f2bf(a.y); o0.z = f2bf(a.z); o0.w = f2bf(a.w);
        o1.x = f2bf(b.x); o1.y = f2bf(b.y); o1.z = f2bf(b.z); o1.w = f2bf(b.w);
        *(ushort4*)(Xb + i) = o0;
        *(ushort4*)(Xb + i + 4) = o1;
    } else {
        *(uint4*)(Xb + i) = *(const uint4*)((const u16*)X + i);
    }
}

// ---------------------------------------------------------------- transpose W
__global__ __launch_bounds__(256) void transpose_w_kernel(
    const void* __restrict__ Wq, const void* __restrict__ Wk,
    const void* __restrict__ Wv, u16* __restrict__ Wt,
    const int* __restrict__ flag)
{
    __shared__ u16 tile[64][72];
    const int t  = threadIdx.x;
    const int k0 = blockIdx.x * 64;
    const int n0 = blockIdx.y * 64;
    const int w  = blockIdx.z;
    const void* W = (w == 0) ? Wq : ((w == 1) ? Wk : Wv);
    const int fp32 = *flag;
#pragma unroll
    for (int it = 0; it < 2; ++it) {
        int idx = t + it * 256;
        int r = idx >> 3;
        int c = (idx & 7) * 8;
        const size_t off = (size_t)(k0 + r) * 1024 + n0 + c;
        if (fp32) {
            const float* Wf = (const float*)W + off;
            float4 a = *(const float4*)Wf;
            float4 b = *(const float4*)(Wf + 4);
            u16* tp = &tile[r][c];
            tp[0] = f2bf(a.x); tp[1] = f2bf(a.y); tp[2] = f2bf(a.z); tp[3] = f2bf(a.w);
            tp[4] = f2bf(b.x); tp[5] = f2bf(b.y); tp[6] = f2bf(b.z); tp[7] = f2bf(b.w);
        } else {
            *(uint4*)&tile[r][c] = *(const uint4*)((const u16*)W + off);
        }
    }
    __syncthreads();
#pragma unroll
    for (int it = 0; it < 2; ++it) {
        int idx = t + it * 256;
        int r = idx >> 3;
        int c = (idx & 7) * 8;
        union { u16 s[8]; uint4 v; } tmp;
#pragma unroll
        for (int j = 0; j < 8; ++j) tmp.s[j] = tile[c + j][r];
        *(uint4*)(Wt + (size_t)(w * 1024 + n0 + r) * 1024 + k0 + c) = tmp.v;
    }
}

// ------------------------------------------------------------ transpose V (4)
// Vt4[b][d][s] = QKV[b*2048+s][2048+d]. grid (32,16,4).
__global__ __launch_bounds__(256) void transpose_v4_kernel(
    const u16* __restrict__ QKV, u16* __restrict__ Vt4)
{
    __shared__ u16 tile[64][72];
    const int t  = threadIdx.x;
    const int k0 = blockIdx.x * 64;     // s
    const int n0 = blockIdx.y * 64;     // d
    const int b  = blockIdx.z;
    const u16* Vsrc = QKV + (size_t)b * 2048 * 3072 + 2048;
    u16* Vt = Vt4 + (size_t)b * 1024 * 2048;
#pragma unroll
    for (int it = 0; it < 2; ++it) {
        int idx = t + it * 256;
        int r = idx >> 3;
        int c = (idx & 7) * 8;
        *(uint4*)&tile[r][c] = *(const uint4*)(Vsrc + (size_t)(k0 + r) * 3072 + n0 + c);
    }
    __syncthreads();
#pragma unroll
    for (int it = 0; it < 2; ++it) {
        int idx = t + it * 256;
        int r = idx >> 3;
        int c = (idx & 7) * 8;
        union { u16 s[8]; uint4 v; } tmp;
#pragma unroll
        for (int j = 0; j < 8; ++j) tmp.s[j] = tile[c + j][r];
        *(uint4*)(Vt + (size_t)(n0 + r) * 2048 + k0 + c) = tmp.v;
    }
}

// ----------------------------------------------------------- GEMM 128x128x32
// C[M][N] = A[M][K] @ Bt[N][K]^T * scale (+bias), bf16 in/out, fp32 accum.
// EPI 0: +bias3[col] lookup. EPI 1: scale only.
// 256 thr = 4 waves; wave (wr,wc) computes 64x64 via 4x4 16x16x32 MFMAs.
// Staging: global_load_lds width 16; LDS unpadded [128][32] (m104 constraint).
template<int EPI>
__global__ __launch_bounds__(256) void gemm128(
    const u16* __restrict__ A, int lda, size_t sA,
    const u16* __restrict__ Bt, int ldb, size_t sB,
    u16* __restrict__ C, int ldc, size_t sC,
    int K, float scale, const u16* __restrict__ bias3)
{
    __shared__ u16 As[128 * 32];
    __shared__ u16 Bs[128 * 32];
    const int t    = threadIdx.x;
    const int lane = t & 63;
    const int w    = t >> 6;
    const int wr   = w >> 1, wc = w & 1;
    const int quad = lane >> 4, l16 = lane & 15;
    const int m0 = blockIdx.y * 128;
    const int n0 = blockIdx.x * 128;
    const int b  = blockIdx.z;
    A  += (size_t)b * sA;
    Bt += (size_t)b * sB;
    C  += (size_t)b * sC;

    // staging: wave w covers 32 rows [w*32, w*32+32) in 2 instrs of 16 rows;
    // lane i -> row (i>>2), col (i&3)*8; HW scatters to ldsbase + lane*16B.
    const int srow = lane >> 2;
    const int scol = (lane & 3) * 8;
    const u16* Ag0 = A  + (size_t)(m0 + w * 32 +      srow) * lda + scol;
    const u16* Ag1 = A  + (size_t)(m0 + w * 32 + 16 + srow) * lda + scol;
    const u16* Bg0 = Bt + (size_t)(n0 + w * 32 +      srow) * ldb + scol;
    const u16* Bg1 = Bt + (size_t)(n0 + w * 32 + 16 + srow) * ldb + scol;
    u16* Al0 = As + (w * 32) * 32;
    u16* Al1 = As + (w * 32 + 16) * 32;
    u16* Bl0 = Bs + (w * 32) * 32;
    u16* Bl1 = Bs + (w * 32 + 16) * 32;

    f32x4 acc[4][4];
#pragma unroll
    for (int mi = 0; mi < 4; ++mi)
#pragma unroll
        for (int ni = 0; ni < 4; ++ni)
            acc[mi][ni] = (f32x4){0.f, 0.f, 0.f, 0.f};

    for (int k0 = 0; k0 < K; k0 += 32) {
        load_lds16(Ag0 + k0, Al0);
        load_lds16(Ag1 + k0, Al1);
        load_lds16(Bg0 + k0, Bl0);
        load_lds16(Bg1 + k0, Bl1);
        __syncthreads();                 // compiler drains vmcnt before barrier
        bf16x8 af[4], bfr[4];
#pragma unroll
        for (int i = 0; i < 4; ++i) {
            af[i]  = *(const bf16x8*)&As[(wr * 64 + i * 16 + l16) * 32 + quad * 8];
            bfr[i] = *(const bf16x8*)&Bs[(wc * 64 + i * 16 + l16) * 32 + quad * 8];
        }
#pragma unroll
        for (int mi = 0; mi < 4; ++mi)
#pragma unroll
            for (int ni = 0; ni < 4; ++ni)
                acc[mi][ni] = __builtin_amdgcn_mfma_f32_16x16x32_bf16(
                    af[mi], bfr[ni], acc[mi][ni], 0, 0, 0);
        __syncthreads();
    }

    // C/D layout (m89): col = lane&15, row = quad*4 + reg
    const int row0 = m0 + wr * 64 + quad * 4;
    const int col0 = n0 + wc * 64 + l16;
#pragma unroll
    for (int mi = 0; mi < 4; ++mi) {
#pragma unroll
        for (int ni = 0; ni < 4; ++ni) {
            const int col = col0 + ni * 16;
            const float bias = (EPI == 0) ? bf2f(bias3[col]) : 0.f;
#pragma unroll
            for (int r = 0; r < 4; ++r) {
                const int row = row0 + mi * 16 + r;
                C[(size_t)row * ldc + col] = f2bf(acc[mi][ni][r] * scale + bias);
            }
        }
    }
}

// ----------------------------------------------------------- softmax (bf16)
// In-place row softmax on S4: 8192 rows x 2048 bf16. block 256, 8 elems/thr.
__global__ __launch_bounds__(256) void softmax_bf16_kernel(u16* __restrict__ S)
{
    const int t = threadIdx.x;
    u16* sp = S + (size_t)blockIdx.x * 2048;
    union { uint4 v; u16 h[8]; } raw;
    raw.v = *(const uint4*)(sp + t * 8);
    float vals[8];
#pragma unroll
    for (int i = 0; i < 8; ++i) vals[i] = bf2f(raw.h[i]);
    float m = vals[0];
#pragma unroll
    for (int i = 1; i < 8; ++i) m = fmaxf(m, vals[i]);
#pragma unroll
    for (int off = 32; off > 0; off >>= 1) m = fmaxf(m, __shfl_xor(m, off));
    __shared__ float red[8];
    const int w = t >> 6, lane = t & 63;
    if (lane == 0) red[w] = m;
    __syncthreads();
    m = fmaxf(fmaxf(red[0], red[1]), fmaxf(red[2], red[3]));
    float e[8], s = 0.f;
#pragma unroll
    for (int i = 0; i < 8; ++i) { e[i] = __expf(vals[i] - m); s += e[i]; }
#pragma unroll
    for (int off = 32; off > 0; off >>= 1) s += __shfl_xor(s, off);
    if (lane == 0) red[4 + w] = s;
    __syncthreads();
    s = red[4] + red[5] + red[6] + red[7];
    const float rinv = 1.f / s;
    union { uint4 v; u16 h[8]; } out;
#pragma unroll
    for (int i = 0; i < 8; ++i) out.h[i] = f2bf(e[i] * rinv);
    *(uint4*)(sp + t * 8) = out.v;
}

// ---------------------------------------------------------------- resid + LN
__global__ __launch_bounds__(256) void resid_ln_kernel(
    const u16* __restrict__ Ctx, const u16* __restrict__ Xb,
    const u16* __restrict__ gamma, const u16* __restrict__ beta,
    void* __restrict__ Out, const int* __restrict__ flag)
{
    const size_t row = blockIdx.x;
    const int t = threadIdx.x;
    ushort4 cv = *(const ushort4*)(Ctx + row * 3072 + t * 4);
    ushort4 xv = *(const ushort4*)(Xb + row * 1024 + t * 4);
    float v[4] = {bf2f(cv.x) + bf2f(xv.x), bf2f(cv.y) + bf2f(xv.y),
                  bf2f(cv.z) + bf2f(xv.z), bf2f(cv.w) + bf2f(xv.w)};
    float s  = v[0] + v[1] + v[2] + v[3];
    float s2 = v[0] * v[0] + v[1] * v[1] + v[2] * v[2] + v[3] * v[3];
#pragma unroll
    for (int off = 32; off > 0; off >>= 1) {
        s  += __shfl_xor(s, off);
        s2 += __shfl_xor(s2, off);
    }
    __shared__ float red[8];
    const int w = t >> 6, lane = t & 63;
    if (lane == 0) { red[w] = s; red[4 + w] = s2; }
    __syncthreads();
    s  = red[0] + red[1] + red[2] + red[3];
    s2 = red[4] + red[5] + red[6] + red[7];
    const float mu  = s * (1.f / 1024.f);
    const float var = s2 * (1.f / 1024.f) - mu * mu;
    const float inv = rsqrtf(var + 1e-3f);
    ushort4 gv = *(const ushort4*)(gamma + t * 4);
    ushort4 bv = *(const ushort4*)(beta + t * 4);
    float o[4];
    o[0] = (v[0] - mu) * inv * bf2f(gv.x) + bf2f(bv.x);
    o[1] = (v[1] - mu) * inv * bf2f(gv.y) + bf2f(bv.y);
    o[2] = (v[2] - mu) * inv * bf2f(gv.z) + bf2f(bv.z);
    o[3] = (v[3] - mu) * inv * bf2f(gv.w) + bf2f(bv.w);
    if (*flag) {
        float4 fo = {o[0], o[1], o[2], o[3]};
        *(float4*)((float*)Out + row * 1024 + t * 4) = fo;
    } else {
        ushort4 bo;
        bo.x = f2bf(o[0]); bo.y = f2bf(o[1]); bo.z = f2bf(o[2]); bo.w = f2bf(o[3]);
        *(ushort4*)((u16*)Out + row * 1024 + t * 4) = bo;
    }
}

// ---------------------------------------------------------------- launch
extern "C" void kernel_launch(void* const* d_in, const int* in_sizes, int n_in,
                              void* d_out, int out_size, void* d_ws, size_t ws_size,
                              hipStream_t stream)
{
    (void)in_sizes; (void)n_in; (void)out_size; (void)ws_size;
    const void* X     = d_in[0];
    const void* Wq    = d_in[1];
    const void* bq    = d_in[2];
    const void* Wk    = d_in[3];
    const void* bk    = d_in[4];
    const void* Wv    = d_in[5];
    const void* bv    = d_in[6];
    const void* gamma = d_in[7];
    const void* beta  = d_in[8];

    char* ws = (char*)d_ws;
    int* flag  = (int*)(ws + 0);
    u16* bias5 = (u16*)(ws + 16);
    u16* Wt    = (u16*)(ws + 16384);
    u16* QKV   = (u16*)(ws + 6307840);
    u16* Xb    = (u16*)(ws + 56639488);
    u16* S4    = (u16*)(ws + 73416704);      // scores -> P, bf16, 4 batches
    u16* Vt4   = (u16*)(ws + 106971136);

    detect_mode_kernel<<<1, 64, 0, stream>>>((const u16*)X, flag);
    convert_small_kernel<<<5, 256, 0, stream>>>(bq, bk, bv, gamma, beta, bias5, flag);
    convert_x_kernel<<<4096, 256, 0, stream>>>(X, Xb, flag);
    transpose_w_kernel<<<dim3(16, 16, 3), 256, 0, stream>>>(Wq, Wk, Wv, Wt, flag);

    // QKV = Xb @ Wt^T + bias   (M=8192, N=3072, K=1024)
    gemm128<0><<<dim3(24, 64, 1), 256, 0, stream>>>(
        Xb, 1024, 0, Wt, 1024, 0, QKV, 3072, 0, 1024, 1.f, bias5);

    // S4[b] = (Q_b @ K_b^T)/32   (M=N=2048, K=1024, z=4)
    gemm128<1><<<dim3(16, 16, 4), 256, 0, stream>>>(
        QKV, 3072, (size_t)2048 * 3072,
        QKV + 1024, 3072, (size_t)2048 * 3072,
        S4, 2048, (size_t)2048 * 2048, 1024, 0.03125f, nullptr);

    softmax_bf16_kernel<<<8192, 256, 0, stream>>>(S4);
    transpose_v4_kernel<<<dim3(32, 16, 4), 256, 0, stream>>>(QKV, Vt4);

    // Ctx_b = P_b @ V_b -> QKV Q slots   (M=2048, N=1024, K=2048, z=4)
    gemm128<1><<<dim3(8, 16, 4), 256, 0, stream>>>(
        S4, 2048, (size_t)2048 * 2048,
        Vt4, 2048, (size_t)1024 * 2048,
        QKV, 3072, (size_t)2048 * 3072, 2048, 1.f, nullptr);

    resid_ln_kernel<<<8192, 256, 0, stream>>>(
        QKV, Xb, bias5 + 3 * 1024, bias5 + 4 * 1024, d_out, flag);
}

// Round 5
// 305.055 us; speedup vs baseline: 1.5586x; 1.0898x over previous
//
#include <hip/hip_runtime.h>
#include <hip/hip_bf16.h>
#include <cstdint>
#include <cstddef>

// B=4, S=2048, D=1024. Inputs fp32 (runtime-detected, bf16 fallback kept).
// GEMMs: 128x128 tile, BK=64 (two 16KB slabs), global_load_lds width-16
// staging with XOR kgroup swizzle, 4 waves x (2x2) 32x32x16 bf16 MFMAs.
//
// Pipeline:
//   0. detect_mode; convert bias/gamma/beta + X -> bf16; transpose W -> Wt
//   1. gemm128<0>: QKV[8192][3072] = Xb @ Wt^T + bias               (bf16)
//   2. gemm128<1> z=4: S4[b][2048][2048] = (Q_b @ K_b^T)/32         (bf16)
//   3. softmax_bf16: in-place row softmax on S4 -> P                (bf16)
//   4. transpose_v4 z=4: Vt4[b][1024][2048] = V_b^T
//   5. gemm128<1> z=4: Ctx_b = P_b @ V_b -> dead Q slots of QKV     (bf16)
//   6. resid_ln: out = LN(Ctx + Xb)*gamma + beta (fp32 or bf16 store)
//
// d_ws layout (16B-aligned, ~118 MB):
//   flag  @ 0            16
//   bias5 @ 16           10,240
//   Wt    @ 16,384       6,291,456
//   QKV   @ 6,307,840    50,331,648
//   Xb    @ 56,639,488   16,777,216
//   S4/P4 @ 73,416,704   33,554,432
//   Vt4   @ 106,971,136  16,777,216   (end 123,748,352)

typedef unsigned short u16;
using bf16x8 = __attribute__((ext_vector_type(8))) short;
using f32x16 = __attribute__((ext_vector_type(16))) float;

typedef __attribute__((address_space(3))) unsigned int lds_uint;
typedef const __attribute__((address_space(1))) unsigned int glob_uint;

__device__ __forceinline__ float bf2f(u16 h) {
    union { unsigned int u; float f; } c;
    c.u = ((unsigned int)h) << 16;
    return c.f;
}
__device__ __forceinline__ u16 f2bf(float f) {
    union { float f; unsigned int u; } c;
    c.f = f;
    return (u16)((c.u + 0x7fffu + ((c.u >> 16) & 1u)) >> 16);  // RNE
}
__device__ __forceinline__ void load_lds16(const void* g, void* l) {
    __builtin_amdgcn_global_load_lds((glob_uint*)g, (lds_uint*)l, 16, 0, 0);
}

// ------------------------------------------------------------- mode detection
__global__ void detect_mode_kernel(const u16* __restrict__ X, int* __restrict__ flag)
{
    const int lane = threadIdx.x;      // 64 threads
    bool bad = false, nz = false;
    for (int j = 0; j < 4; ++j) {
        float v = bf2f(X[(lane * 4 + j) * 2]);
        if (!(fabsf(v) <= 1e9f)) bad = true;
        if (v != 0.f) nz = true;
    }
    unsigned long long anybad = __ballot(bad);
    unsigned long long anynz  = __ballot(nz);
    if (lane == 0) *flag = (anybad != 0ull || anynz == 0ull) ? 1 : 0;
}

// --------------------------------------------------- small vectors -> bf16
__global__ __launch_bounds__(256) void convert_small_kernel(
    const void* s0, const void* s1, const void* s2, const void* s3,
    const void* s4, u16* __restrict__ dst, const int* __restrict__ flag)
{
    const void* srcs[5] = {s0, s1, s2, s3, s4};
    const void* src = srcs[blockIdx.x];
    u16* d = dst + (size_t)blockIdx.x * 1024;
    const int i = threadIdx.x * 4;
    if (*flag) {
        const float* f = (const float*)src;
        ushort4 o;
        o.x = f2bf(f[i]); o.y = f2bf(f[i + 1]);
        o.z = f2bf(f[i + 2]); o.w = f2bf(f[i + 3]);
        *(ushort4*)(d + i) = o;
    } else {
        *(ushort4*)(d + i) = *(const ushort4*)((const u16*)src + i);
    }
}

// --------------------------------------------------------------- X -> bf16
__global__ __launch_bounds__(256) void convert_x_kernel(
    const void* __restrict__ X, u16* __restrict__ Xb, const int* __restrict__ flag)
{
    const size_t i = ((size_t)blockIdx.x * 256 + threadIdx.x) * 8;
    if (*flag) {
        const float* f = (const float*)X;
        float4 a = *(const float4*)(f + i);
        float4 b = *(const float4*)(f + i + 4);
        ushort4 o0, o1;
        o0.x = f2bf(a.x); o0.y = f2bf(a.y); o0.z = f2bf(a.z); o0.w = f2bf(a.w);
        o1.x = f2bf(b.x); o1.y = f2bf(b.y); o1.z = f2bf(b.z); o1.w = f2bf(b.w);
        *(ushort4*)(Xb + i) = o0;
        *(ushort4*)(Xb + i + 4) = o1;
    } else {
        *(uint4*)(Xb + i) = *(const uint4*)((const u16*)X + i);
    }
}

// ---------------------------------------------------------------- transpose W
__global__ __launch_bounds__(256) void transpose_w_kernel(
    const void* __restrict__ Wq, const void* __restrict__ Wk,
    const void* __restrict__ Wv, u16* __restrict__ Wt,
    const int* __restrict__ flag)
{
    __shared__ u16 tile[64][72];
    const int t  = threadIdx.x;
    const int k0 = blockIdx.x * 64;
    const int n0 = blockIdx.y * 64;
    const int w  = blockIdx.z;
    const void* W = (w == 0) ? Wq : ((w == 1) ? Wk : Wv);
    const int fp32 = *flag;
#pragma unroll
    for (int it = 0; it < 2; ++it) {
        int idx = t + it * 256;
        int r = idx >> 3;
        int c = (idx & 7) * 8;
        const size_t off = (size_t)(k0 + r) * 1024 + n0 + c;
        if (fp32) {
            const float* Wf = (const float*)W + off;
            float4 a = *(const float4*)Wf;
            float4 b = *(const float4*)(Wf + 4);
            u16* tp = &tile[r][c];
            tp[0] = f2bf(a.x); tp[1] = f2bf(a.y); tp[2] = f2bf(a.z); tp[3] = f2bf(a.w);
            tp[4] = f2bf(b.x); tp[5] = f2bf(b.y); tp[6] = f2bf(b.z); tp[7] = f2bf(b.w);
        } else {
            *(uint4*)&tile[r][c] = *(const uint4*)((const u16*)W + off);
        }
    }
    __syncthreads();
#pragma unroll
    for (int it = 0; it < 2; ++it) {
        int idx = t + it * 256;
        int r = idx >> 3;
        int c = (idx & 7) * 8;
        union { u16 s[8]; uint4 v; } tmp;
#pragma unroll
        for (int j = 0; j < 8; ++j) tmp.s[j] = tile[c + j][r];
        *(uint4*)(Wt + (size_t)(w * 1024 + n0 + r) * 1024 + k0 + c) = tmp.v;
    }
}

// ------------------------------------------------------------ transpose V (4)
__global__ __launch_bounds__(256) void transpose_v4_kernel(
    const u16* __restrict__ QKV, u16* __restrict__ Vt4)
{
    __shared__ u16 tile[64][72];
    const int t  = threadIdx.x;
    const int k0 = blockIdx.x * 64;     // s
    const int n0 = blockIdx.y * 64;     // d
    const int b  = blockIdx.z;
    const u16* Vsrc = QKV + (size_t)b * 2048 * 3072 + 2048;
    u16* Vt = Vt4 + (size_t)b * 1024 * 2048;
#pragma unroll
    for (int it = 0; it < 2; ++it) {
        int idx = t + it * 256;
        int r = idx >> 3;
        int c = (idx & 7) * 8;
        *(uint4*)&tile[r][c] = *(const uint4*)(Vsrc + (size_t)(k0 + r) * 3072 + n0 + c);
    }
    __syncthreads();
#pragma unroll
    for (int it = 0; it < 2; ++it) {
        int idx = t + it * 256;
        int r = idx >> 3;
        int c = (idx & 7) * 8;
        union { u16 s[8]; uint4 v; } tmp;
#pragma unroll
        for (int j = 0; j < 8; ++j) tmp.s[j] = tile[c + j][r];
        *(uint4*)(Vt + (size_t)(n0 + r) * 2048 + k0 + c) = tmp.v;
    }
}

// ----------------------------------------------------------- GEMM 128x128x64
// C[M][N] = A[M][K] @ Bt[N][K]^T * scale (+bias), bf16 in/out, fp32 accum.
// 256 thr = 4 waves; wave (wr,wc) computes 64x64 via 2x2 32x32x16 MFMAs.
// BK=64 as two [128][32] slabs per operand (32 KB LDS). Staging via
// global_load_lds w/ XOR kgroup swizzle: lane i stages (row=i>>2,
// kg=(i&3)^((i>>2)&3)); readers use slot = g ^ (lane&3) (all strip bases
// are 0 mod 4) -> perfect 8 words/bank spread for the 32-row frag reads.
template<int EPI>
__global__ __launch_bounds__(256) void gemm128(
    const u16* __restrict__ A, int lda, size_t sA,
    const u16* __restrict__ Bt, int ldb, size_t sB,
    u16* __restrict__ C, int ldc, size_t sC,
    int K, float scale, const u16* __restrict__ bias3)
{
    __shared__ u16 As[2][128 * 32];
    __shared__ u16 Bs[2][128 * 32];
    const int t    = threadIdx.x;
    const int lane = t & 63;
    const int w    = t >> 6;
    const int wr   = w >> 1, wc = w & 1;
    const int m0 = blockIdx.y * 128;
    const int n0 = blockIdx.x * 128;
    A  += (size_t)blockIdx.z * sA;
    Bt += (size_t)blockIdx.z * sB;
    C  += (size_t)blockIdx.z * sC;

    // swizzled staging addresses (wave w covers rows [w*32, w*32+32))
    const int srow = lane >> 2;
    const int skg  = (lane & 3) ^ (srow & 3);         // row&3 invariant mod 16/32
    const u16* Ag0 = A  + (size_t)(m0 + w * 32 +      srow) * lda + skg * 8;
    const u16* Ag1 = A  + (size_t)(m0 + w * 32 + 16 + srow) * lda + skg * 8;
    const u16* Bg0 = Bt + (size_t)(n0 + w * 32 +      srow) * ldb + skg * 8;
    const u16* Bg1 = Bt + (size_t)(n0 + w * 32 + 16 + srow) * ldb + skg * 8;
    u16* Al0 = &As[0][(w * 32) * 32];
    u16* Al1 = &As[1][(w * 32) * 32];
    u16* Bl0 = &Bs[0][(w * 32) * 32];
    u16* Bl1 = &Bs[1][(w * 32) * 32];

    f32x16 acc[2][2];
#pragma unroll
    for (int mi = 0; mi < 2; ++mi)
#pragma unroll
        for (int ni = 0; ni < 2; ++ni)
#pragma unroll
            for (int r = 0; r < 16; ++r)
                acc[mi][ni][r] = 0.f;

    const int ml   = lane & 31;
    const int kh   = lane >> 5;          // khalf
    const int lxor = lane & 3;

    for (int k0 = 0; k0 < K; k0 += 64) {
        load_lds16(Ag0 + k0,      Al0);
        load_lds16(Ag1 + k0,      Al0 + 16 * 32);
        load_lds16(Bg0 + k0,      Bl0);
        load_lds16(Bg1 + k0,      Bl0 + 16 * 32);
        load_lds16(Ag0 + k0 + 32, Al1);
        load_lds16(Ag1 + k0 + 32, Al1 + 16 * 32);
        load_lds16(Bg0 + k0 + 32, Bl1);
        load_lds16(Bg1 + k0 + 32, Bl1 + 16 * 32);
        __syncthreads();
#pragma unroll
        for (int slab = 0; slab < 2; ++slab) {
            const u16* as_ = As[slab];
            const u16* bs_ = Bs[slab];
#pragma unroll
            for (int s = 0; s < 2; ++s) {
                const int g    = s * 2 + kh;             // kgroup within slab
                const int slot = (g ^ lxor) * 8;
                bf16x8 a0 = *(const bf16x8*)&as_[(wr * 64 +      ml) * 32 + slot];
                bf16x8 a1 = *(const bf16x8*)&as_[(wr * 64 + 32 + ml) * 32 + slot];
                bf16x8 b0 = *(const bf16x8*)&bs_[(wc * 64 +      ml) * 32 + slot];
                bf16x8 b1 = *(const bf16x8*)&bs_[(wc * 64 + 32 + ml) * 32 + slot];
                acc[0][0] = __builtin_amdgcn_mfma_f32_32x32x16_bf16(a0, b0, acc[0][0], 0, 0, 0);
                acc[0][1] = __builtin_amdgcn_mfma_f32_32x32x16_bf16(a0, b1, acc[0][1], 0, 0, 0);
                acc[1][0] = __builtin_amdgcn_mfma_f32_32x32x16_bf16(a1, b0, acc[1][0], 0, 0, 0);
                acc[1][1] = __builtin_amdgcn_mfma_f32_32x32x16_bf16(a1, b1, acc[1][1], 0, 0, 0);
            }
        }
        __syncthreads();
    }

    // C/D layout (m74/m101): col = lane&31, row = (reg&3) + 8*(reg>>2) + 4*(lane>>5)
    const int colb = n0 + wc * 64 + ml;
    const int rowb = m0 + wr * 64 + 4 * kh;
#pragma unroll
    for (int mi = 0; mi < 2; ++mi) {
#pragma unroll
        for (int ni = 0; ni < 2; ++ni) {
            const int col = colb + ni * 32;
            const float bias = (EPI == 0) ? bf2f(bias3[col]) : 0.f;
#pragma unroll
            for (int r = 0; r < 16; ++r) {
                const int row = rowb + mi * 32 + (r & 3) + 8 * (r >> 2);
                C[(size_t)row * ldc + col] = f2bf(acc[mi][ni][r] * scale + bias);
            }
        }
    }
}

// ----------------------------------------------------------- softmax (bf16)
__global__ __launch_bounds__(256) void softmax_bf16_kernel(u16* __restrict__ S)
{
    const int t = threadIdx.x;
    u16* sp = S + (size_t)blockIdx.x * 2048;
    union { uint4 v; u16 h[8]; } raw;
    raw.v = *(const uint4*)(sp + t * 8);
    float vals[8];
#pragma unroll
    for (int i = 0; i < 8; ++i) vals[i] = bf2f(raw.h[i]);
    float m = vals[0];
#pragma unroll
    for (int i = 1; i < 8; ++i) m = fmaxf(m, vals[i]);
#pragma unroll
    for (int off = 32; off > 0; off >>= 1) m = fmaxf(m, __shfl_xor(m, off));
    __shared__ float red[8];
    const int w = t >> 6, lane = t & 63;
    if (lane == 0) red[w] = m;
    __syncthreads();
    m = fmaxf(fmaxf(red[0], red[1]), fmaxf(red[2], red[3]));
    float e[8], s = 0.f;
#pragma unroll
    for (int i = 0; i < 8; ++i) { e[i] = __expf(vals[i] - m); s += e[i]; }
#pragma unroll
    for (int off = 32; off > 0; off >>= 1) s += __shfl_xor(s, off);
    if (lane == 0) red[4 + w] = s;
    __syncthreads();
    s = red[4] + red[5] + red[6] + red[7];
    const float rinv = 1.f / s;
    union { uint4 v; u16 h[8]; } out;
#pragma unroll
    for (int i = 0; i < 8; ++i) out.h[i] = f2bf(e[i] * rinv);
    *(uint4*)(sp + t * 8) = out.v;
}

// ---------------------------------------------------------------- resid + LN
__global__ __launch_bounds__(256) void resid_ln_kernel(
    const u16* __restrict__ Ctx, const u16* __restrict__ Xb,
    const u16* __restrict__ gamma, const u16* __restrict__ beta,
    void* __restrict__ Out, const int* __restrict__ flag)
{
    const size_t row = blockIdx.x;
    const int t = threadIdx.x;
    ushort4 cv = *(const ushort4*)(Ctx + row * 3072 + t * 4);
    ushort4 xv = *(const ushort4*)(Xb + row * 1024 + t * 4);
    float v[4] = {bf2f(cv.x) + bf2f(xv.x), bf2f(cv.y) + bf2f(xv.y),
                  bf2f(cv.z) + bf2f(xv.z), bf2f(cv.w) + bf2f(xv.w)};
    float s  = v[0] + v[1] + v[2] + v[3];
    float s2 = v[0] * v[0] + v[1] * v[1] + v[2] * v[2] + v[3] * v[3];
#pragma unroll
    for (int off = 32; off > 0; off >>= 1) {
        s  += __shfl_xor(s, off);
        s2 += __shfl_xor(s2, off);
    }
    __shared__ float red[8];
    const int w = t >> 6, lane = t & 63;
    if (lane == 0) { red[w] = s; red[4 + w] = s2; }
    __syncthreads();
    s  = red[0] + red[1] + red[2] + red[3];
    s2 = red[4] + red[5] + red[6] + red[7];
    const float mu  = s * (1.f / 1024.f);
    const float var = s2 * (1.f / 1024.f) - mu * mu;
    const float inv = rsqrtf(var + 1e-3f);
    ushort4 gv = *(const ushort4*)(gamma + t * 4);
    ushort4 bv = *(const ushort4*)(beta + t * 4);
    float o[4];
    o[0] = (v[0] - mu) * inv * bf2f(gv.x) + bf2f(bv.x);
    o[1] = (v[1] - mu) * inv * bf2f(gv.y) + bf2f(bv.y);
    o[2] = (v[2] - mu) * inv * bf2f(gv.z) + bf2f(bv.z);
    o[3] = (v[3] - mu) * inv * bf2f(gv.w) + bf2f(bv.w);
    if (*flag) {
        float4 fo = {o[0], o[1], o[2], o[3]};
        *(float4*)((float*)Out + row * 1024 + t * 4) = fo;
    } else {
        ushort4 bo;
        bo.x = f2bf(o[0]); bo.y = f2bf(o[1]); bo.z = f2bf(o[2]); bo.w = f2bf(o[3]);
        *(ushort4*)((u16*)Out + row * 1024 + t * 4) = bo;
    }
}

// ---------------------------------------------------------------- launch
extern "C" void kernel_launch(void* const* d_in, const int* in_sizes, int n_in,
                              void* d_out, int out_size, void* d_ws, size_t ws_size,
                              hipStream_t stream)
{
    (void)in_sizes; (void)n_in; (void)out_size; (void)ws_size;
    const void* X     = d_in[0];
    const void* Wq    = d_in[1];
    const void* bq    = d_in[2];
    const void* Wk    = d_in[3];
    const void* bk    = d_in[4];
    const void* Wv    = d_in[5];
    const void* bv    = d_in[6];
    const void* gamma = d_in[7];
    const void* beta  = d_in[8];

    char* ws = (char*)d_ws;
    int* flag  = (int*)(ws + 0);
    u16* bias5 = (u16*)(ws + 16);
    u16* Wt    = (u16*)(ws + 16384);
    u16* QKV   = (u16*)(ws + 6307840);
    u16* Xb    = (u16*)(ws + 56639488);
    u16* S4    = (u16*)(ws + 73416704);
    u16* Vt4   = (u16*)(ws + 106971136);

    detect_mode_kernel<<<1, 64, 0, stream>>>((const u16*)X, flag);
    convert_small_kernel<<<5, 256, 0, stream>>>(bq, bk, bv, gamma, beta, bias5, flag);
    convert_x_kernel<<<4096, 256, 0, stream>>>(X, Xb, flag);
    transpose_w_kernel<<<dim3(16, 16, 3), 256, 0, stream>>>(Wq, Wk, Wv, Wt, flag);

    // QKV = Xb @ Wt^T + bias   (M=8192, N=3072, K=1024)
    gemm128<0><<<dim3(24, 64, 1), 256, 0, stream>>>(
        Xb, 1024, 0, Wt, 1024, 0, QKV, 3072, 0, 1024, 1.f, bias5);

    // S4[b] = (Q_b @ K_b^T)/32   (M=N=2048, K=1024, z=4)
    gemm128<1><<<dim3(16, 16, 4), 256, 0, stream>>>(
        QKV, 3072, (size_t)2048 * 3072,
        QKV + 1024, 3072, (size_t)2048 * 3072,
        S4, 2048, (size_t)2048 * 2048, 1024, 0.03125f, nullptr);

    softmax_bf16_kernel<<<8192, 256, 0, stream>>>(S4);
    transpose_v4_kernel<<<dim3(32, 16, 4), 256, 0, stream>>>(QKV, Vt4);

    // Ctx_b = P_b @ V_b -> QKV Q slots   (M=2048, N=1024, K=2048, z=4)
    gemm128<1><<<dim3(8, 16, 4), 256, 0, stream>>>(
        S4, 2048, (size_t)2048 * 2048,
        Vt4, 2048, (size_t)1024 * 2048,
        QKV, 3072, (size_t)2048 * 3072, 2048, 1.f, nullptr);

    resid_ln_kernel<<<8192, 256, 0, stream>>>(
        QKV, Xb, bias5 + 3 * 1024, bias5 + 4 * 1024, d_out, flag);
}

// Round 6
// 297.103 us; speedup vs baseline: 1.6003x; 1.0268x over previous
//
#include <hip/hip_runtime.h>
#include <hip/hip_bf16.h>
#include <cstdint>
#include <cstddef>

// B=4, S=2048, D=1024. Inputs fp32 (runtime-detected, bf16 fallback kept).
// GEMMs: 128x128 tile, BK=64 (two 16KB slabs), global_load_lds width-16
// staging with XOR kgroup swizzle (key=(row>>1)&3 — parity-independent,
// uniform 8 words/bank), 4 waves x (2x2) 32x32x16 bf16 MFMAs.
//
// Pipeline:
//   0. detect_mode; convert bias/gamma/beta + X -> bf16; transpose W -> Wt
//   1. gemm128<0>: QKV[8192][3072] = Xb @ Wt^T + bias               (bf16)
//   2. gemm128<1> z=4: S4[b][2048][2048] = (Q_b @ K_b^T)/32         (bf16)
//   3. softmax_bf16: in-place row softmax on S4 -> P                (bf16)
//   4. transpose_v4 z=4: Vt4[b][1024][2048] = V_b^T
//   5. gemm128<1> z=4: Ctx_b = P_b @ V_b -> dead Q slots of QKV     (bf16)
//   6. resid_ln: out = LN(Ctx + Xb)*gamma + beta (fp32 or bf16 store)
//
// d_ws layout (16B-aligned, ~118 MB):
//   flag  @ 0            16
//   bias5 @ 16           10,240
//   Wt    @ 16,384       6,291,456
//   QKV   @ 6,307,840    50,331,648
//   Xb    @ 56,639,488   16,777,216
//   S4/P4 @ 73,416,704   33,554,432
//   Vt4   @ 106,971,136  16,777,216   (end 123,748,352)

typedef unsigned short u16;
using bf16x8 = __attribute__((ext_vector_type(8))) short;
using f32x16 = __attribute__((ext_vector_type(16))) float;

typedef __attribute__((address_space(3))) unsigned int lds_uint;
typedef const __attribute__((address_space(1))) unsigned int glob_uint;

__device__ __forceinline__ float bf2f(u16 h) {
    union { unsigned int u; float f; } c;
    c.u = ((unsigned int)h) << 16;
    return c.f;
}
__device__ __forceinline__ u16 f2bf(float f) {
    union { float f; unsigned int u; } c;
    c.f = f;
    return (u16)((c.u + 0x7fffu + ((c.u >> 16) & 1u)) >> 16);  // RNE
}
__device__ __forceinline__ void load_lds16(const void* g, void* l) {
    __builtin_amdgcn_global_load_lds((glob_uint*)g, (lds_uint*)l, 16, 0, 0);
}

// ------------------------------------------------------------- mode detection
__global__ void detect_mode_kernel(const u16* __restrict__ X, int* __restrict__ flag)
{
    const int lane = threadIdx.x;      // 64 threads
    bool bad = false, nz = false;
    for (int j = 0; j < 4; ++j) {
        float v = bf2f(X[(lane * 4 + j) * 2]);
        if (!(fabsf(v) <= 1e9f)) bad = true;
        if (v != 0.f) nz = true;
    }
    unsigned long long anybad = __ballot(bad);
    unsigned long long anynz  = __ballot(nz);
    if (lane == 0) *flag = (anybad != 0ull || anynz == 0ull) ? 1 : 0;
}

// --------------------------------------------------- small vectors -> bf16
__global__ __launch_bounds__(256) void convert_small_kernel(
    const void* s0, const void* s1, const void* s2, const void* s3,
    const void* s4, u16* __restrict__ dst, const int* __restrict__ flag)
{
    const void* srcs[5] = {s0, s1, s2, s3, s4};
    const void* src = srcs[blockIdx.x];
    u16* d = dst + (size_t)blockIdx.x * 1024;
    const int i = threadIdx.x * 4;
    if (*flag) {
        const float* f = (const float*)src;
        ushort4 o;
        o.x = f2bf(f[i]); o.y = f2bf(f[i + 1]);
        o.z = f2bf(f[i + 2]); o.w = f2bf(f[i + 3]);
        *(ushort4*)(d + i) = o;
    } else {
        *(ushort4*)(d + i) = *(const ushort4*)((const u16*)src + i);
    }
}

// --------------------------------------------------------------- X -> bf16
__global__ __launch_bounds__(256) void convert_x_kernel(
    const void* __restrict__ X, u16* __restrict__ Xb, const int* __restrict__ flag)
{
    const size_t i = ((size_t)blockIdx.x * 256 + threadIdx.x) * 8;
    if (*flag) {
        const float* f = (const float*)X;
        float4 a = *(const float4*)(f + i);
        float4 b = *(const float4*)(f + i + 4);
        ushort4 o0, o1;
        o0.x = f2bf(a.x); o0.y = f2bf(a.y); o0.z = f2bf(a.z); o0.w = f2bf(a.w);
        o1.x = f2bf(b.x); o1.y = f2bf(b.y); o1.z = f2bf(b.z); o1.w = f2bf(b.w);
        *(ushort4*)(Xb + i) = o0;
        *(ushort4*)(Xb + i + 4) = o1;
    } else {
        *(uint4*)(Xb + i) = *(const uint4*)((const u16*)X + i);
    }
}

// ---------------------------------------------------------------- transpose W
__global__ __launch_bounds__(256) void transpose_w_kernel(
    const void* __restrict__ Wq, const void* __restrict__ Wk,
    const void* __restrict__ Wv, u16* __restrict__ Wt,
    const int* __restrict__ flag)
{
    __shared__ u16 tile[64][72];
    const int t  = threadIdx.x;
    const int k0 = blockIdx.x * 64;
    const int n0 = blockIdx.y * 64;
    const int w  = blockIdx.z;
    const void* W = (w == 0) ? Wq : ((w == 1) ? Wk : Wv);
    const int fp32 = *flag;
#pragma unroll
    for (int it = 0; it < 2; ++it) {
        int idx = t + it * 256;
        int r = idx >> 3;
        int c = (idx & 7) * 8;
        const size_t off = (size_t)(k0 + r) * 1024 + n0 + c;
        if (fp32) {
            const float* Wf = (const float*)W + off;
            float4 a = *(const float4*)Wf;
            float4 b = *(const float4*)(Wf + 4);
            u16* tp = &tile[r][c];
            tp[0] = f2bf(a.x); tp[1] = f2bf(a.y); tp[2] = f2bf(a.z); tp[3] = f2bf(a.w);
            tp[4] = f2bf(b.x); tp[5] = f2bf(b.y); tp[6] = f2bf(b.z); tp[7] = f2bf(b.w);
        } else {
            *(uint4*)&tile[r][c] = *(const uint4*)((const u16*)W + off);
        }
    }
    __syncthreads();
#pragma unroll
    for (int it = 0; it < 2; ++it) {
        int idx = t + it * 256;
        int r = idx >> 3;
        int c = (idx & 7) * 8;
        union { u16 s[8]; uint4 v; } tmp;
#pragma unroll
        for (int j = 0; j < 8; ++j) tmp.s[j] = tile[c + j][r];
        *(uint4*)(Wt + (size_t)(w * 1024 + n0 + r) * 1024 + k0 + c) = tmp.v;
    }
}

// ------------------------------------------------------------ transpose V (4)
__global__ __launch_bounds__(256) void transpose_v4_kernel(
    const u16* __restrict__ QKV, u16* __restrict__ Vt4)
{
    __shared__ u16 tile[64][72];
    const int t  = threadIdx.x;
    const int k0 = blockIdx.x * 64;     // s
    const int n0 = blockIdx.y * 64;     // d
    const int b  = blockIdx.z;
    const u16* Vsrc = QKV + (size_t)b * 2048 * 3072 + 2048;
    u16* Vt = Vt4 + (size_t)b * 1024 * 2048;
#pragma unroll
    for (int it = 0; it < 2; ++it) {
        int idx = t + it * 256;
        int r = idx >> 3;
        int c = (idx & 7) * 8;
        *(uint4*)&tile[r][c] = *(const uint4*)(Vsrc + (size_t)(k0 + r) * 3072 + n0 + c);
    }
    __syncthreads();
#pragma unroll
    for (int it = 0; it < 2; ++it) {
        int idx = t + it * 256;
        int r = idx >> 3;
        int c = (idx & 7) * 8;
        union { u16 s[8]; uint4 v; } tmp;
#pragma unroll
        for (int j = 0; j < 8; ++j) tmp.s[j] = tile[c + j][r];
        *(uint4*)(Vt + (size_t)(n0 + r) * 2048 + k0 + c) = tmp.v;
    }
}

// ----------------------------------------------------------- GEMM 128x128x64
// C[M][N] = A[M][K] @ Bt[N][K]^T * scale (+bias), bf16 in/out, fp32 accum.
// 256 thr = 4 waves; wave (wr,wc) computes 64x64 via 2x2 32x32x16 MFMAs.
// BK=64 as two [128][32] slabs per operand (32 KB LDS).
// XOR kgroup swizzle with key=(row>>1)&3: parity-independent, so the
// 32-row x 2-kgroup frag read spreads 256 words uniformly 8/bank.
// Staging lane i fetches global kgroup (i&3)^((i>>3)&3) — LDS dest stays
// the contiguous DMA pattern (m104 constraint).
template<int EPI>
__global__ __launch_bounds__(256) void gemm128(
    const u16* __restrict__ A, int lda, size_t sA,
    const u16* __restrict__ Bt, int ldb, size_t sB,
    u16* __restrict__ C, int ldc, size_t sC,
    int K, float scale, const u16* __restrict__ bias3)
{
    __shared__ u16 As[2][128 * 32];
    __shared__ u16 Bs[2][128 * 32];
    const int t    = threadIdx.x;
    const int lane = t & 63;
    const int w    = t >> 6;
    const int wr   = w >> 1, wc = w & 1;
    const int m0 = blockIdx.y * 128;
    const int n0 = blockIdx.x * 128;
    A  += (size_t)blockIdx.z * sA;
    Bt += (size_t)blockIdx.z * sB;
    C  += (size_t)blockIdx.z * sC;

    // swizzled staging (wave w covers rows [w*32, w*32+32)); key = (srow>>1)&3
    const int srow = lane >> 2;
    const int skg  = (lane & 3) ^ ((srow >> 1) & 3);
    const u16* Ag0 = A  + (size_t)(m0 + w * 32 +      srow) * lda + skg * 8;
    const u16* Ag1 = A  + (size_t)(m0 + w * 32 + 16 + srow) * lda + skg * 8;
    const u16* Bg0 = Bt + (size_t)(n0 + w * 32 +      srow) * ldb + skg * 8;
    const u16* Bg1 = Bt + (size_t)(n0 + w * 32 + 16 + srow) * ldb + skg * 8;
    u16* Al0 = &As[0][(w * 32) * 32];
    u16* Al1 = &As[1][(w * 32) * 32];
    u16* Bl0 = &Bs[0][(w * 32) * 32];
    u16* Bl1 = &Bs[1][(w * 32) * 32];

    f32x16 acc[2][2];
#pragma unroll
    for (int mi = 0; mi < 2; ++mi)
#pragma unroll
        for (int ni = 0; ni < 2; ++ni)
#pragma unroll
            for (int r = 0; r < 16; ++r)
                acc[mi][ni][r] = 0.f;

    const int ml  = lane & 31;
    const int kh  = lane >> 5;           // khalf
    const int key = (ml >> 1) & 3;       // parity-independent swizzle key

    for (int k0 = 0; k0 < K; k0 += 64) {
        load_lds16(Ag0 + k0,      Al0);
        load_lds16(Ag1 + k0,      Al0 + 16 * 32);
        load_lds16(Bg0 + k0,      Bl0);
        load_lds16(Bg1 + k0,      Bl0 + 16 * 32);
        load_lds16(Ag0 + k0 + 32, Al1);
        load_lds16(Ag1 + k0 + 32, Al1 + 16 * 32);
        load_lds16(Bg0 + k0 + 32, Bl1);
        load_lds16(Bg1 + k0 + 32, Bl1 + 16 * 32);
        __syncthreads();
#pragma unroll
        for (int slab = 0; slab < 2; ++slab) {
            const u16* as_ = As[slab];
            const u16* bs_ = Bs[slab];
#pragma unroll
            for (int s = 0; s < 2; ++s) {
                const int g    = s * 2 + kh;             // kgroup within slab
                const int slot = (g ^ key) * 8;
                bf16x8 a0 = *(const bf16x8*)&as_[(wr * 64 +      ml) * 32 + slot];
                bf16x8 a1 = *(const bf16x8*)&as_[(wr * 64 + 32 + ml) * 32 + slot];
                bf16x8 b0 = *(const bf16x8*)&bs_[(wc * 64 +      ml) * 32 + slot];
                bf16x8 b1 = *(const bf16x8*)&bs_[(wc * 64 + 32 + ml) * 32 + slot];
                acc[0][0] = __builtin_amdgcn_mfma_f32_32x32x16_bf16(a0, b0, acc[0][0], 0, 0, 0);
                acc[0][1] = __builtin_amdgcn_mfma_f32_32x32x16_bf16(a0, b1, acc[0][1], 0, 0, 0);
                acc[1][0] = __builtin_amdgcn_mfma_f32_32x32x16_bf16(a1, b0, acc[1][0], 0, 0, 0);
                acc[1][1] = __builtin_amdgcn_mfma_f32_32x32x16_bf16(a1, b1, acc[1][1], 0, 0, 0);
            }
        }
        __syncthreads();
    }

    // C/D layout (m74/m101): col = lane&31, row = (reg&3) + 8*(reg>>2) + 4*(lane>>5)
    const int colb = n0 + wc * 64 + ml;
    const int rowb = m0 + wr * 64 + 4 * kh;
#pragma unroll
    for (int mi = 0; mi < 2; ++mi) {
#pragma unroll
        for (int ni = 0; ni < 2; ++ni) {
            const int col = colb + ni * 32;
            const float bias = (EPI == 0) ? bf2f(bias3[col]) : 0.f;
#pragma unroll
            for (int r = 0; r < 16; ++r) {
                const int row = rowb + mi * 32 + (r & 3) + 8 * (r >> 2);
                C[(size_t)row * ldc + col] = f2bf(acc[mi][ni][r] * scale + bias);
            }
        }
    }
}

// ----------------------------------------------------------- softmax (bf16)
__global__ __launch_bounds__(256) void softmax_bf16_kernel(u16* __restrict__ S)
{
    const int t = threadIdx.x;
    u16* sp = S + (size_t)blockIdx.x * 2048;
    union { uint4 v; u16 h[8]; } raw;
    raw.v = *(const uint4*)(sp + t * 8);
    float vals[8];
#pragma unroll
    for (int i = 0; i < 8; ++i) vals[i] = bf2f(raw.h[i]);
    float m = vals[0];
#pragma unroll
    for (int i = 1; i < 8; ++i) m = fmaxf(m, vals[i]);
#pragma unroll
    for (int off = 32; off > 0; off >>= 1) m = fmaxf(m, __shfl_xor(m, off));
    __shared__ float red[8];
    const int w = t >> 6, lane = t & 63;
    if (lane == 0) red[w] = m;
    __syncthreads();
    m = fmaxf(fmaxf(red[0], red[1]), fmaxf(red[2], red[3]));
    float e[8], s = 0.f;
#pragma unroll
    for (int i = 0; i < 8; ++i) { e[i] = __expf(vals[i] - m); s += e[i]; }
#pragma unroll
    for (int off = 32; off > 0; off >>= 1) s += __shfl_xor(s, off);
    if (lane == 0) red[4 + w] = s;
    __syncthreads();
    s = red[4] + red[5] + red[6] + red[7];
    const float rinv = 1.f / s;
    union { uint4 v; u16 h[8]; } out;
#pragma unroll
    for (int i = 0; i < 8; ++i) out.h[i] = f2bf(e[i] * rinv);
    *(uint4*)(sp + t * 8) = out.v;
}

// ---------------------------------------------------------------- resid + LN
__global__ __launch_bounds__(256) void resid_ln_kernel(
    const u16* __restrict__ Ctx, const u16* __restrict__ Xb,
    const u16* __restrict__ gamma, const u16* __restrict__ beta,
    void* __restrict__ Out, const int* __restrict__ flag)
{
    const size_t row = blockIdx.x;
    const int t = threadIdx.x;
    ushort4 cv = *(const ushort4*)(Ctx + row * 3072 + t * 4);
    ushort4 xv = *(const ushort4*)(Xb + row * 1024 + t * 4);
    float v[4] = {bf2f(cv.x) + bf2f(xv.x), bf2f(cv.y) + bf2f(xv.y),
                  bf2f(cv.z) + bf2f(xv.z), bf2f(cv.w) + bf2f(xv.w)};
    float s  = v[0] + v[1] + v[2] + v[3];
    float s2 = v[0] * v[0] + v[1] * v[1] + v[2] * v[2] + v[3] * v[3];
#pragma unroll
    for (int off = 32; off > 0; off >>= 1) {
        s  += __shfl_xor(s, off);
        s2 += __shfl_xor(s2, off);
    }
    __shared__ float red[8];
    const int w = t >> 6, lane = t & 63;
    if (lane == 0) { red[w] = s; red[4 + w] = s2; }
    __syncthreads();
    s  = red[0] + red[1] + red[2] + red[3];
    s2 = red[4] + red[5] + red[6] + red[7];
    const float mu  = s * (1.f / 1024.f);
    const float var = s2 * (1.f / 1024.f) - mu * mu;
    const float inv = rsqrtf(var + 1e-3f);
    ushort4 gv = *(const ushort4*)(gamma + t * 4);
    ushort4 bv = *(const ushort4*)(beta + t * 4);
    float o[4];
    o[0] = (v[0] - mu) * inv * bf2f(gv.x) + bf2f(bv.x);
    o[1] = (v[1] - mu) * inv * bf2f(gv.y) + bf2f(bv.y);
    o[2] = (v[2] - mu) * inv * bf2f(gv.z) + bf2f(bv.z);
    o[3] = (v[3] - mu) * inv * bf2f(gv.w) + bf2f(bv.w);
    if (*flag) {
        float4 fo = {o[0], o[1], o[2], o[3]};
        *(float4*)((float*)Out + row * 1024 + t * 4) = fo;
    } else {
        ushort4 bo;
        bo.x = f2bf(o[0]); bo.y = f2bf(o[1]); bo.z = f2bf(o[2]); bo.w = f2bf(o[3]);
        *(ushort4*)((u16*)Out + row * 1024 + t * 4) = bo;
    }
}

// ---------------------------------------------------------------- launch
extern "C" void kernel_launch(void* const* d_in, const int* in_sizes, int n_in,
                              void* d_out, int out_size, void* d_ws, size_t ws_size,
                              hipStream_t stream)
{
    (void)in_sizes; (void)n_in; (void)out_size; (void)ws_size;
    const void* X     = d_in[0];
    const void* Wq    = d_in[1];
    const void* bq    = d_in[2];
    const void* Wk    = d_in[3];
    const void* bk    = d_in[4];
    const void* Wv    = d_in[5];
    const void* bv    = d_in[6];
    const void* gamma = d_in[7];
    const void* beta  = d_in[8];

    char* ws = (char*)d_ws;
    int* flag  = (int*)(ws + 0);
    u16* bias5 = (u16*)(ws + 16);
    u16* Wt    = (u16*)(ws + 16384);
    u16* QKV   = (u16*)(ws + 6307840);
    u16* Xb    = (u16*)(ws + 56639488);
    u16* S4    = (u16*)(ws + 73416704);
    u16* Vt4   = (u16*)(ws + 106971136);

    detect_mode_kernel<<<1, 64, 0, stream>>>((const u16*)X, flag);
    convert_small_kernel<<<5, 256, 0, stream>>>(bq, bk, bv, gamma, beta, bias5, flag);
    convert_x_kernel<<<4096, 256, 0, stream>>>(X, Xb, flag);
    transpose_w_kernel<<<dim3(16, 16, 3), 256, 0, stream>>>(Wq, Wk, Wv, Wt, flag);

    // QKV = Xb @ Wt^T + bias   (M=8192, N=3072, K=1024)
    gemm128<0><<<dim3(24, 64, 1), 256, 0, stream>>>(
        Xb, 1024, 0, Wt, 1024, 0, QKV, 3072, 0, 1024, 1.f, bias5);

    // S4[b] = (Q_b @ K_b^T)/32   (M=N=2048, K=1024, z=4)
    gemm128<1><<<dim3(16, 16, 4), 256, 0, stream>>>(
        QKV, 3072, (size_t)2048 * 3072,
        QKV + 1024, 3072, (size_t)2048 * 3072,
        S4, 2048, (size_t)2048 * 2048, 1024, 0.03125f, nullptr);

    softmax_bf16_kernel<<<8192, 256, 0, stream>>>(S4);
    transpose_v4_kernel<<<dim3(32, 16, 4), 256, 0, stream>>>(QKV, Vt4);

    // Ctx_b = P_b @ V_b -> QKV Q slots   (M=2048, N=1024, K=2048, z=4)
    gemm128<1><<<dim3(8, 16, 4), 256, 0, stream>>>(
        S4, 2048, (size_t)2048 * 2048,
        Vt4, 2048, (size_t)1024 * 2048,
        QKV, 3072, (size_t)2048 * 3072, 2048, 1.f, nullptr);

    resid_ln_kernel<<<8192, 256, 0, stream>>>(
        QKV, Xb, bias5 + 3 * 1024, bias5 + 4 * 1024, d_out, flag);
}